// Round 10
// baseline (249.653 us; speedup 1.0000x reference)
//
#include <hip/hip_runtime.h>

// Partitioned MHA: x(4,2048,1024) fp32 -> (out_c, out_p) each (4,2048,512) fp32.
// R10: k_attn PV consumes P directly from registers via v_mfma_f32_16x16x16
// (builtin _1k): swapped-QK S^T layout (HW-verified R7/R9: lane = P[q=m16+li]
// [k=n16+4lg+r]) IS the x16 B-fragment layout. P LDS round-trip deleted
// (ds_write+lgkm+ds_read+conflicts); LDS 36.9->16.4KB. O/ls switch to x16 C/D
// layout (col=li=q, row=4lg+r=d) -> packed uint2 O stores. Rest frozen (R9).

typedef __attribute__((ext_vector_type(8))) short bf16x8;
typedef __attribute__((ext_vector_type(4))) short bf16x4;
typedef __attribute__((ext_vector_type(4))) float f32x4;
typedef unsigned short u16;

#define QSCALE 0.18033688011112042f  // (1/sqrt(64)) * log2(e): max-free softmax uses exp2(s)

__device__ __forceinline__ u16 f2bf(float f){
  unsigned u = __builtin_bit_cast(unsigned, f);
  u += 0x7FFFu + ((u >> 16) & 1u);
  return (u16)(u >> 16);
}

__device__ __forceinline__ unsigned cvtpk(float lo, float hi){
  unsigned r;
  asm("v_cvt_pk_bf16_f32 %0, %1, %2" : "=v"(r) : "v"(lo), "v"(hi));
  return r;
}

__device__ __forceinline__ f32x4 mfma16(bf16x4 a, bf16x4 b, f32x4 c){
  return __builtin_amdgcn_mfma_f32_16x16x16bf16_1k(a, b, c, 0, 0, 0);
}

__device__ __forceinline__ void gload16(const void* g, void* l){
  __builtin_amdgcn_global_load_lds(
    (const __attribute__((address_space(1))) unsigned*)g,
    (__attribute__((address_space(3))) unsigned*)l, 16, 0, 0);
}

// ---------- x fp32 -> bf16 ----------
__global__ __launch_bounds__(256) void k_cvt_x(const float4* __restrict__ x, uint2* __restrict__ xb){
  int i = blockIdx.x*256 + threadIdx.x;
  float4 v = x[i];
  uint2 o;
  o.x = (unsigned)f2bf(v.x) | ((unsigned)f2bf(v.y) << 16);
  o.y = (unsigned)f2bf(v.z) | ((unsigned)f2bf(v.w) << 16);
  xb[i] = o;
}

// ---------- repack w_qkv (16,512,3,32)x2 fp32 -> wt[part*16+h][ca=96][f=512] bf16 ----------
__global__ __launch_bounds__(256) void k_repack_qkv(const float* __restrict__ wc, const float* __restrict__ wp,
                                                    u16* __restrict__ wt){
  int i = blockIdx.x*256 + threadIdx.x;
  int f  = i & 511;
  int ca = (i >> 9) % 96;
  int ph = (i >> 9) / 96;
  const float* src = (ph < 16) ? wc : wp;
  wt[i] = f2bf(src[(ph & 15)*49152 + f*96 + ca]);
}

// ---------- repack w_o (16,32,512)x2 fp32 -> wot[part][f=512][k=512] bf16 ----------
__global__ __launch_bounds__(256) void k_repack_wo(const float* __restrict__ wc, const float* __restrict__ wp,
                                                   u16* __restrict__ wt){
  int i = blockIdx.x*256 + threadIdx.x;
  int k = i & 511;
  int f = (i >> 9) & 511;
  int part = i >> 18;
  const float* src = part ? wp : wc;
  wt[i] = f2bf(src[k*512 + f]);
}

// ---------- QKV projection: 256-token blocks, wave owns 64 rows (R8, XCD-affine) ----------
__global__ __launch_bounds__(256) void k_qkv(const u16* __restrict__ xb, const u16* __restrict__ wt,
                                             u16* __restrict__ Q, u16* __restrict__ K, u16* __restrict__ VT){
  const int lane = threadIdx.x & 63, wv = threadIdx.x >> 6;
  const int lg = lane >> 4, li = lane & 15;
  const int blk = blockIdx.x;
  const int xcd = blk & 7, idx = blk >> 3;
  const int tt  = (idx >> 5)*8 + xcd;
  const int ph  = idx & 31;
  const int row0 = tt*256 + wv*64;
  const int part = ph >> 4, h = ph & 15;

  f32x4 acc[4][6] = {};
  const u16* wbase = wt + (size_t)ph*96*512;
  #pragma unroll 2
  for (int ks = 0; ks < 16; ++ks){
    bf16x8 a[4], b[6];
    #pragma unroll
    for (int m=0;m<4;++m)
      a[m] = *(const bf16x8*)(xb + (size_t)(row0 + m*16 + li)*1024 + part*512 + ks*32 + lg*8);
    #pragma unroll
    for (int n=0;n<6;++n)
      b[n] = *(const bf16x8*)(wbase + (size_t)(n*16 + li)*512 + ks*32 + lg*8);
    #pragma unroll
    for (int m=0;m<4;++m)
      #pragma unroll
      for (int n=0;n<6;++n)
        acc[m][n] = __builtin_amdgcn_mfma_f32_16x16x32_bf16(a[m], b[n], acc[m][n], 0, 0, 0);
  }

  const int b_ = row0 >> 11;
  const int bh = b_*16 + h;
  const int tl0 = (row0 & 2047) + lg*4;
  #pragma unroll
  for (int m=0;m<4;++m){
    #pragma unroll
    for (int n=0;n<6;++n){
      const int c = n >> 1;
      const int af = part*32 + (n & 1)*16 + li;
      if (c == 2){
        uint2 pk;
        pk.x = (unsigned)f2bf(acc[m][n][0]) | ((unsigned)f2bf(acc[m][n][1]) << 16);
        pk.y = (unsigned)f2bf(acc[m][n][2]) | ((unsigned)f2bf(acc[m][n][3]) << 16);
        *(uint2*)(VT + (size_t)(bh*64 + af)*2048 + tl0 + m*16) = pk;
      } else {
        u16* dst = (c == 0) ? Q : K;
        const float sc = (c == 0) ? QSCALE : 1.0f;
        #pragma unroll
        for (int r=0;r<4;++r){
          int tl = tl0 + m*16 + r;
          dst[((size_t)bh*2048 + tl)*64 + af] = f2bf(acc[m][n][r] * sc);
        }
      }
    }
  }
}

// ---------- flash attention (max-free softmax; in-register P -> x16 PV) ----------
// grid 1024 (XCD-swizzled). 4 waves * 32 q-rows. KV tile = 32 keys.
// LDS: K0@0 K1@4096 | V0@8192 V1@12288. Total 16384 B. No P buffer.
#define NKT 64
__global__ __launch_bounds__(256, 4) void k_attn(const u16* __restrict__ Q, const u16* __restrict__ K,
                                                 const u16* __restrict__ VT, u16* __restrict__ O){
  __shared__ __align__(16) char smem[16384];
  const int lane = threadIdx.x & 63, w = threadIdx.x >> 6;
  const int lg = lane >> 4, li = lane & 15;
  const int swz = (blockIdx.x & 7)*128 + (blockIdx.x >> 3);   // XCD-contiguous
  const int bh = swz >> 4, qt = swz & 15;
  const int q0 = qt*128 + w*32;

  const char* Kg = (const char*)(K  + (size_t)bh*131072);
  const char* Vg = (const char*)(VT + (size_t)bh*131072);
  const u16*  Qb = Q + (size_t)bh*131072;

  const unsigned ksrc = (unsigned)((w*8 + (lane>>3))*128 + (((lane&7) ^ (lane>>3)) << 4));
  const unsigned vsrc0 = (unsigned)((w*16 + (lane>>2))*4096 + (((lane&3) ^ ((lane>>2)&3)) << 4));
  const unsigned ldst = (unsigned)(w*1024);

  const unsigned kc0 = (unsigned)(((     lg) ^ (li&7)) << 4);
  const unsigned kc1 = (unsigned)(((4 +  lg) ^ (li&7)) << 4);

  bf16x8 aq[2][2];
  #pragma unroll
  for (int m=0;m<2;++m)
    #pragma unroll
    for (int kd=0;kd<2;++kd)
      aq[m][kd] = *(const bf16x8*)(Qb + (size_t)(q0 + m*16 + li)*64 + kd*32 + lg*8);

  const short ob = (short)0x3F80;
  const bf16x4 ones4 = {ob, ob, ob, ob};

  f32x4 o16[2][4] = {};   // [m][nd]: O^T[d=nd*16+4lg+r][q=m*16+li]
  f32x4 ls16[2] = {};     // [m]: rowsum for q=m*16+li (all 4 regs equal)

  auto COMPUTE = [&](const char* sK, const char* sV){
    uint2 pq[2][2];                      // [m][n]: P[q=m*16+li][k=n*16+4lg..+3]
    #pragma unroll
    for (int n=0;n<2;++n){
      bf16x8 bk0 = *(const bf16x8*)(sK + (n*16 + li)*128 + kc0);
      bf16x8 bk1 = *(const bf16x8*)(sK + (n*16 + li)*128 + kc1);
      #pragma unroll
      for (int m=0;m<2;++m){
        f32x4 s = {0.f,0.f,0.f,0.f};     // S^T: row k=n*16+4lg+r, col q=m*16+li
        s = __builtin_amdgcn_mfma_f32_16x16x32_bf16(bk0, aq[m][0], s, 0, 0, 0);
        s = __builtin_amdgcn_mfma_f32_16x16x32_bf16(bk1, aq[m][1], s, 0, 0, 0);
        pq[m][n].x = cvtpk(__builtin_exp2f(s[0]), __builtin_exp2f(s[1]));
        pq[m][n].y = cvtpk(__builtin_exp2f(s[2]), __builtin_exp2f(s[3]));
      }
    }
    __builtin_amdgcn_s_setprio(1);
    #pragma unroll
    for (int nd=0;nd<4;++nd){
      #pragma unroll
      for (int n=0;n<2;++n){
        // A = V^T frag: lane holds V^T[d=nd*16+li][k=n*16+4lg..+3] (b64, XOR-swz)
        const unsigned chunk = (unsigned)((n*2 + (lg>>1)) ^ (li&3));
        uint2 avu = *(const uint2*)(sV + (nd*16 + li)*64 + chunk*16 + (lg&1)*8);
        bf16x4 av = __builtin_bit_cast(bf16x4, avu);
        o16[0][nd] = mfma16(av, __builtin_bit_cast(bf16x4, pq[0][n]), o16[0][nd]);
        o16[1][nd] = mfma16(av, __builtin_bit_cast(bf16x4, pq[1][n]), o16[1][nd]);
      }
    }
    #pragma unroll
    for (int n=0;n<2;++n){
      ls16[0] = mfma16(ones4, __builtin_bit_cast(bf16x4, pq[0][n]), ls16[0]);
      ls16[1] = mfma16(ones4, __builtin_bit_cast(bf16x4, pq[1][n]), ls16[1]);
    }
    __builtin_amdgcn_s_setprio(0);
  };

  // prologue: stage tile 0 -> buf 0
  gload16(Kg + ksrc,  smem + ldst);
  gload16(Vg + vsrc0, smem + 8192 + ldst);
  asm volatile("s_waitcnt vmcnt(0)" ::: "memory");
  __builtin_amdgcn_s_barrier();

  for (int kt = 0; kt < NKT; ++kt){
    if (kt + 1 < NKT){
      gload16(Kg + (kt+1)*4096u + ksrc, smem + ((kt+1)&1)*4096 + ldst);
      gload16(Vg + (kt+1)*64u + vsrc0,  smem + 8192 + ((kt+1)&1)*4096 + ldst);
    }
    COMPUTE(smem + (kt&1)*4096, smem + 8192 + (kt&1)*4096);
    asm volatile("s_waitcnt vmcnt(0)" ::: "memory");
    __builtin_amdgcn_s_barrier();
  }

  // store O [b*2048+t][h*64+d] bf16; lane holds 4 consecutive d per (m,nd)
  const int b_ = bh >> 4, h = bh & 15;
  #pragma unroll
  for (int m=0;m<2;++m){
    const float linv = 1.0f / ls16[m][0];
    const int t = q0 + m*16 + li;
    u16* obase = O + ((size_t)b_*2048 + t)*1024 + h*64;
    #pragma unroll
    for (int nd=0;nd<4;++nd){
      uint2 pk;
      pk.x = (unsigned)f2bf(o16[m][nd][0]*linv) | ((unsigned)f2bf(o16[m][nd][1]*linv) << 16);
      pk.y = (unsigned)f2bf(o16[m][nd][2]*linv) | ((unsigned)f2bf(o16[m][nd][3]*linv) << 16);
      *(uint2*)(obase + nd*16 + lg*4) = pk;
    }
  }
}

// ---------- output projection (R8, XCD-affine) ----------
__global__ __launch_bounds__(256) void k_proj(const u16* __restrict__ O, const u16* __restrict__ wot,
                                              float* __restrict__ out){
  const int lane = threadIdx.x & 63, wv = threadIdx.x >> 6;
  const int lg = lane >> 4, li = lane & 15;
  const int blk = blockIdx.x;
  const int xcd = blk & 7, idx = blk >> 3;
  const int rowTile = (idx >> 3)*8 + xcd;
  const int colTile = idx & 7;
  const int row0 = rowTile*128 + wv*32;
  const int col0 = colTile*128;
  const int part = col0 >> 9;
  const int f0 = col0 & 511;

  f32x4 acc[2][8] = {};
  #pragma unroll 4
  for (int ks = 0; ks < 16; ++ks){
    bf16x8 a[2];
    #pragma unroll
    for (int m=0;m<2;++m)
      a[m] = *(const bf16x8*)(O + (size_t)(row0 + m*16 + li)*1024 + ks*64 + part*32 + lg*8);
    #pragma unroll
    for (int n=0;n<8;++n){
      bf16x8 b = *(const bf16x8*)(wot + (size_t)part*262144 + (size_t)(f0 + n*16 + li)*512 + ks*32 + lg*8);
      #pragma unroll
      for (int m=0;m<2;++m)
        acc[m][n] = __builtin_amdgcn_mfma_f32_16x16x32_bf16(a[m], b, acc[m][n], 0, 0, 0);
    }
  }
  float* obp = out + (size_t)part*(8192u*512u);
  #pragma unroll
  for (int m=0;m<2;++m)
    #pragma unroll
    for (int n=0;n<8;++n)
      #pragma unroll
      for (int r=0;r<4;++r)
        obp[(size_t)(row0 + m*16 + lg*4 + r)*512 + f0 + n*16 + li] = acc[m][n][r];
}

extern "C" void kernel_launch(void* const* d_in, const int* in_sizes, int n_in,
                              void* d_out, int out_size, void* d_ws, size_t ws_size,
                              hipStream_t stream){
  const float* x   = (const float*)d_in[0];
  const float* wqc = (const float*)d_in[1];
  const float* wqp = (const float*)d_in[2];
  const float* woc = (const float*)d_in[3];
  const float* wop = (const float*)d_in[4];

  char* ws = (char*)d_ws;
  u16* xb  = (u16*)(ws);
  u16* Q   = (u16*)(ws + 16777216);
  u16* K   = (u16*)(ws + 2*16777216);
  u16* VT  = (u16*)(ws + 3*16777216);
  u16* wqt = (u16*)(ws + 4*16777216);
  u16* wot = (u16*)(ws + 4*16777216 + 3145728);
  u16* O   = xb;   // xb dead after k_qkv
  float* out = (float*)d_out;

  k_cvt_x     <<<8192, 256, 0, stream>>>((const float4*)x, (uint2*)xb);
  k_repack_qkv<<<6144, 256, 0, stream>>>(wqc, wqp, wqt);
  k_repack_wo <<<2048, 256, 0, stream>>>(woc, wop, wot);
  k_qkv       <<<1024, 256, 0, stream>>>(xb, wqt, Q, K, VT);
  k_attn      <<<1024, 256, 0, stream>>>(Q, K, VT, O);
  k_proj      <<<512,  256, 0, stream>>>(O, wot, out);
}

// Round 11
// 207.098 us; speedup vs baseline: 1.2055x; 1.2055x over previous
//
#include <hip/hip_runtime.h>

// Partitioned MHA: x(4,2048,1024) fp32 -> (out_c, out_p) each (4,2048,512) fp32.
// R11: k_attn reverted to R9 (verified fastest: P ping-pong pipeline, 114.6us;
// R10's x16 path doubled MFMA issue + conflicts). NEW: wqt/wot repacked
// FRAGMENT-MAJOR ([ph][ks][n][lane*8]) so every weight b128 load in
// k_qkv/k_proj is a contiguous 1KB wave segment (was 16x64B scatter = 2x L2
// transactions). Pure permutation — absmax must stay exactly 1.2207e-4.

typedef __attribute__((ext_vector_type(8))) short bf16x8;
typedef __attribute__((ext_vector_type(4))) float f32x4;
typedef unsigned short u16;

#define QSCALE 0.18033688011112042f  // (1/sqrt(64)) * log2(e): max-free softmax uses exp2(s)

__device__ __forceinline__ u16 f2bf(float f){
  unsigned u = __builtin_bit_cast(unsigned, f);
  u += 0x7FFFu + ((u >> 16) & 1u);
  return (u16)(u >> 16);
}

__device__ __forceinline__ unsigned cvtpk(float lo, float hi){
  unsigned r;
  asm("v_cvt_pk_bf16_f32 %0, %1, %2" : "=v"(r) : "v"(lo), "v"(hi));
  return r;
}

__device__ __forceinline__ void gload16(const void* g, void* l){
  __builtin_amdgcn_global_load_lds(
    (const __attribute__((address_space(1))) unsigned*)g,
    (__attribute__((address_space(3))) unsigned*)l, 16, 0, 0);
}

// ---------- x fp32 -> bf16 ----------
__global__ __launch_bounds__(256) void k_cvt_x(const float4* __restrict__ x, uint2* __restrict__ xb){
  int i = blockIdx.x*256 + threadIdx.x;
  float4 v = x[i];
  uint2 o;
  o.x = (unsigned)f2bf(v.x) | ((unsigned)f2bf(v.y) << 16);
  o.y = (unsigned)f2bf(v.z) | ((unsigned)f2bf(v.w) << 16);
  xb[i] = o;
}

// ---------- repack w_qkv -> FRAGMENT-MAJOR wt[ph][ks(16)][n(6)][lane(64)][8] bf16 ----------
// b-frag for (ph,ks,n): lane reads wt + ph*49152 + ks*3072 + n*512 + lane*8 (1KB contig).
// value = src[h][f=ks*32+lg*8+e][c=n>>1][a=(n&1)*16+li]
__global__ __launch_bounds__(256) void k_repack_qkv(const float* __restrict__ wc, const float* __restrict__ wp,
                                                    u16* __restrict__ wt){
  unsigned i = blockIdx.x*256 + threadIdx.x;      // 1,572,864 total
  unsigned ph = i / 49152u;
  unsigned r  = i - ph*49152u;
  unsigned ks = r / 3072u;
  unsigned r2 = r - ks*3072u;
  unsigned n  = r2 >> 9;
  unsigned r3 = r2 & 511u;
  unsigned lg = r3 >> 7, li = (r3 >> 3) & 15u, e = r3 & 7u;
  unsigned h = ph & 15u;
  unsigned f = ks*32u + lg*8u + e;
  const float* src = (ph < 16) ? wc : wp;
  wt[i] = f2bf(src[h*49152u + f*96u + (n>>1)*32u + (n&1u)*16u + li]);
}

// ---------- repack w_o -> FRAGMENT-MAJOR wot[part][ft(4)][ks(16)][n(8)][lane(64)][8] ----------
// b-frag for (part,ft,ks,n): lane reads wot + part*262144 + ft*65536 + ks*4096 + n*512 + lane*8.
// value = src[h=ks][a=(lane>>4)*8+e][f=ft*128+n*16+(lane&15)]  (src is [16 h][32 a][512 f])
__global__ __launch_bounds__(256) void k_repack_wo(const float* __restrict__ wc, const float* __restrict__ wp,
                                                   u16* __restrict__ wt){
  unsigned i = blockIdx.x*256 + threadIdx.x;      // 524,288 total
  unsigned e = i & 7u;
  unsigned lane = (i >> 3) & 63u;
  unsigned n  = (i >> 9) & 7u;
  unsigned ks = (i >> 12) & 15u;
  unsigned ft = (i >> 16) & 3u;
  unsigned part = i >> 18;
  unsigned f = ft*128u + n*16u + (lane & 15u);
  unsigned a = (lane >> 4)*8u + e;
  const float* src = part ? wp : wc;
  wt[i] = f2bf(src[ks*16384u + a*512u + f]);
}

// ---------- QKV projection: 256-token blocks, wave owns 64 rows (XCD-affine) ----------
__global__ __launch_bounds__(256) void k_qkv(const u16* __restrict__ xb, const u16* __restrict__ wt,
                                             u16* __restrict__ Q, u16* __restrict__ K, u16* __restrict__ VT){
  const int lane = threadIdx.x & 63, wv = threadIdx.x >> 6;
  const int lg = lane >> 4, li = lane & 15;
  const int blk = blockIdx.x;
  const int xcd = blk & 7, idx = blk >> 3;
  const int tt  = (idx >> 5)*8 + xcd;
  const int ph  = idx & 31;
  const int row0 = tt*256 + wv*64;
  const int part = ph >> 4, h = ph & 15;

  f32x4 acc[4][6] = {};
  const u16* wbase = wt + (size_t)ph*49152;
  #pragma unroll 2
  for (int ks = 0; ks < 16; ++ks){
    bf16x8 a[4], b[6];
    #pragma unroll
    for (int m=0;m<4;++m)
      a[m] = *(const bf16x8*)(xb + (size_t)(row0 + m*16 + li)*1024 + part*512 + ks*32 + lg*8);
    #pragma unroll
    for (int n=0;n<6;++n)
      b[n] = *(const bf16x8*)(wbase + ks*3072 + n*512 + lane*8);
    #pragma unroll
    for (int m=0;m<4;++m)
      #pragma unroll
      for (int n=0;n<6;++n)
        acc[m][n] = __builtin_amdgcn_mfma_f32_16x16x32_bf16(a[m], b[n], acc[m][n], 0, 0, 0);
  }

  const int b_ = row0 >> 11;
  const int bh = b_*16 + h;
  const int tl0 = (row0 & 2047) + lg*4;
  #pragma unroll
  for (int m=0;m<4;++m){
    #pragma unroll
    for (int n=0;n<6;++n){
      const int c = n >> 1;
      const int af = part*32 + (n & 1)*16 + li;
      if (c == 2){
        uint2 pk;
        pk.x = (unsigned)f2bf(acc[m][n][0]) | ((unsigned)f2bf(acc[m][n][1]) << 16);
        pk.y = (unsigned)f2bf(acc[m][n][2]) | ((unsigned)f2bf(acc[m][n][3]) << 16);
        *(uint2*)(VT + (size_t)(bh*64 + af)*2048 + tl0 + m*16) = pk;
      } else {
        u16* dst = (c == 0) ? Q : K;
        const float sc = (c == 0) ? QSCALE : 1.0f;
        #pragma unroll
        for (int r=0;r<4;++r){
          int tl = tl0 + m*16 + r;
          dst[((size_t)bh*2048 + tl)*64 + af] = f2bf(acc[m][n][r] * sc);
        }
      }
    }
  }
}

// ---------- flash attention (R9-verified: pipelined QK(kt+1) || PV(kt)) ----------
// grid 1024 (XCD-swizzled). 4 waves * 32 q-rows. KV tile = 32 keys.
// LDS: K0@0 K1@4096 | V0@8192 V1@12288 | P 4 waves x 2 copies x [32][40] u16
// @16384 (wave stride 5120, copy stride 2560). Total 36864 B.
#define NKT 64
#define PLD 40
__global__ __launch_bounds__(256, 4) void k_attn(const u16* __restrict__ Q, const u16* __restrict__ K,
                                                 const u16* __restrict__ VT, u16* __restrict__ O){
  __shared__ __align__(16) char smem[36864];
  const int lane = threadIdx.x & 63, w = threadIdx.x >> 6;
  const int lg = lane >> 4, li = lane & 15;
  const int swz = (blockIdx.x & 7)*128 + (blockIdx.x >> 3);   // XCD-contiguous
  const int bh = swz >> 4, qt = swz & 15;
  const int q0 = qt*128 + w*32;

  const char* Kg = (const char*)(K  + (size_t)bh*131072);
  const char* Vg = (const char*)(VT + (size_t)bh*131072);
  const u16*  Qb = Q + (size_t)bh*131072;
  u16* pw = (u16*)(smem + 16384) + w*2560;      // + copy*1280 (u16 units)

  const unsigned ksrc = (unsigned)((w*8 + (lane>>3))*128 + (((lane&7) ^ (lane>>3)) << 4));
  const unsigned vsrc0 = (unsigned)((w*16 + (lane>>2))*4096 + (((lane&3) ^ ((lane>>2)&3)) << 4));
  const unsigned ldst = (unsigned)(w*1024);

  const unsigned kc0 = (unsigned)(((     lg) ^ (li&7)) << 4);
  const unsigned kc1 = (unsigned)(((4 +  lg) ^ (li&7)) << 4);
  const unsigned vc  = (unsigned)(((lg) ^ (li&3)) << 4);

  bf16x8 aq[2][2];
  #pragma unroll
  for (int m=0;m<2;++m)
    #pragma unroll
    for (int kd=0;kd<2;++kd)
      aq[m][kd] = *(const bf16x8*)(Qb + (size_t)(q0 + m*16 + li)*64 + kd*32 + lg*8);

  const short one_bf = (short)0x3F80;
  bf16x8 ones = {one_bf,one_bf,one_bf,one_bf,one_bf,one_bf,one_bf,one_bf};

  f32x4 o[2][4] = {};
  f32x4 ls[2] = {};

  auto QKEXP = [&](const char* sK, u16* pW){
    #pragma unroll
    for (int n=0;n<2;++n){
      bf16x8 bk0 = *(const bf16x8*)(sK + (n*16 + li)*128 + kc0);
      bf16x8 bk1 = *(const bf16x8*)(sK + (n*16 + li)*128 + kc1);
      #pragma unroll
      for (int m=0;m<2;++m){
        f32x4 s = {0.f,0.f,0.f,0.f};   // S^T: row k=n*16+4lg+r, col q=m*16+li
        s = __builtin_amdgcn_mfma_f32_16x16x32_bf16(bk0, aq[m][0], s, 0, 0, 0);
        s = __builtin_amdgcn_mfma_f32_16x16x32_bf16(bk1, aq[m][1], s, 0, 0, 0);
        uint2 pk;
        pk.x = cvtpk(__builtin_exp2f(s[0]), __builtin_exp2f(s[1]));
        pk.y = cvtpk(__builtin_exp2f(s[2]), __builtin_exp2f(s[3]));
        *(uint2*)(pW + (size_t)(m*16 + li)*PLD + n*16 + lg*4) = pk;
      }
    }
  };
  auto PV = [&](const char* sV, const u16* pR){
    bf16x8 pa0 = *(const bf16x8*)(pR + (size_t)(     li)*PLD + lg*8);
    bf16x8 pa1 = *(const bf16x8*)(pR + (size_t)(16 + li)*PLD + lg*8);
    __builtin_amdgcn_s_setprio(1);
    #pragma unroll
    for (int nd=0;nd<4;++nd){
      bf16x8 bv = *(const bf16x8*)(sV + (nd*16 + li)*64 + vc);
      o[0][nd] = __builtin_amdgcn_mfma_f32_16x16x32_bf16(pa0, bv, o[0][nd], 0, 0, 0);
      o[1][nd] = __builtin_amdgcn_mfma_f32_16x16x32_bf16(pa1, bv, o[1][nd], 0, 0, 0);
    }
    ls[0] = __builtin_amdgcn_mfma_f32_16x16x32_bf16(pa0, ones, ls[0], 0, 0, 0);
    ls[1] = __builtin_amdgcn_mfma_f32_16x16x32_bf16(pa1, ones, ls[1], 0, 0, 0);
    __builtin_amdgcn_s_setprio(0);
  };

  // prologue: stage K0,V0,K1; drain; barrier; P(0) -> pbuf0; barrier
  gload16(Kg + ksrc,          smem + ldst);
  gload16(Vg + vsrc0,         smem + 8192 + ldst);
  gload16(Kg + 4096u + ksrc,  smem + 4096 + ldst);
  asm volatile("s_waitcnt vmcnt(0)" ::: "memory");
  __builtin_amdgcn_s_barrier();
  QKEXP(smem, pw);                       // P(0) into copy 0
  __builtin_amdgcn_s_barrier();

  for (int kt = 0; kt < NKT-1; ++kt){
    const int pr = kt & 1, pn = pr ^ 1;
    gload16(Vg + (kt+1)*64u + vsrc0, smem + 8192 + pn*4096 + ldst);
    if (kt + 2 < NKT)
      gload16(Kg + (kt+2)*4096u + ksrc, smem + pr*4096 + ldst);
    QKEXP(smem + pn*4096, pw + pn*1280);
    PV(smem + 8192 + pr*4096, pw + pr*1280);
    asm volatile("s_waitcnt vmcnt(0)" ::: "memory");
    __builtin_amdgcn_s_barrier();
  }
  PV(smem + 8192 + ((NKT-1)&1)*4096, pw + ((NKT-1)&1)*1280);   // PV(63)

  // store O [b*2048+t][h*64+d] bf16 (rowsum complete per lane/reg)
  const int b_ = bh >> 4, h = bh & 15;
  #pragma unroll
  for (int m=0;m<2;++m){
    #pragma unroll
    for (int r=0;r<4;++r){
      float linv = 1.0f / ls[m][r];
      int t = q0 + m*16 + lg*4 + r;
      #pragma unroll
      for (int nd=0;nd<4;++nd)
        O[((size_t)b_*2048 + t)*1024 + h*64 + nd*16 + li] = f2bf(o[m][nd][r] * linv);
    }
  }
}

// ---------- output projection (XCD-affine; fragment-major weights) ----------
__global__ __launch_bounds__(256) void k_proj(const u16* __restrict__ O, const u16* __restrict__ wot,
                                              float* __restrict__ out){
  const int lane = threadIdx.x & 63, wv = threadIdx.x >> 6;
  const int lg = lane >> 4, li = lane & 15;
  const int blk = blockIdx.x;
  const int xcd = blk & 7, idx = blk >> 3;
  const int rowTile = (idx >> 3)*8 + xcd;
  const int colTile = idx & 7;
  const int row0 = rowTile*128 + wv*32;
  const int part = colTile >> 2;
  const int ft   = colTile & 3;
  const int f0   = ft*128;

  f32x4 acc[2][8] = {};
  const u16* wbase = wot + (size_t)part*262144 + (size_t)ft*65536;
  #pragma unroll 4
  for (int ks = 0; ks < 16; ++ks){
    bf16x8 a[2];
    #pragma unroll
    for (int m=0;m<2;++m)
      a[m] = *(const bf16x8*)(O + (size_t)(row0 + m*16 + li)*1024 + ks*64 + part*32 + lg*8);
    #pragma unroll
    for (int n=0;n<8;++n){
      bf16x8 b = *(const bf16x8*)(wbase + ks*4096 + n*512 + lane*8);
      #pragma unroll
      for (int m=0;m<2;++m)
        acc[m][n] = __builtin_amdgcn_mfma_f32_16x16x32_bf16(a[m], b, acc[m][n], 0, 0, 0);
    }
  }
  float* obp = out + (size_t)part*(8192u*512u);
  #pragma unroll
  for (int m=0;m<2;++m)
    #pragma unroll
    for (int n=0;n<8;++n)
      #pragma unroll
      for (int r=0;r<4;++r)
        obp[(size_t)(row0 + m*16 + lg*4 + r)*512 + f0 + n*16 + li] = acc[m][n][r];
}

extern "C" void kernel_launch(void* const* d_in, const int* in_sizes, int n_in,
                              void* d_out, int out_size, void* d_ws, size_t ws_size,
                              hipStream_t stream){
  const float* x   = (const float*)d_in[0];
  const float* wqc = (const float*)d_in[1];
  const float* wqp = (const float*)d_in[2];
  const float* woc = (const float*)d_in[3];
  const float* wop = (const float*)d_in[4];

  char* ws = (char*)d_ws;
  u16* xb  = (u16*)(ws);
  u16* Q   = (u16*)(ws + 16777216);
  u16* K   = (u16*)(ws + 2*16777216);
  u16* VT  = (u16*)(ws + 3*16777216);
  u16* wqt = (u16*)(ws + 4*16777216);
  u16* wot = (u16*)(ws + 4*16777216 + 3145728);
  u16* O   = xb;   // xb dead after k_qkv
  float* out = (float*)d_out;

  k_cvt_x     <<<8192, 256, 0, stream>>>((const float4*)x, (uint2*)xb);
  k_repack_qkv<<<6144, 256, 0, stream>>>(wqc, wqp, wqt);
  k_repack_wo <<<2048, 256, 0, stream>>>(woc, wop, wot);
  k_qkv       <<<1024, 256, 0, stream>>>(xb, wqt, Q, K, VT);
  k_attn      <<<1024, 256, 0, stream>>>(Q, K, VT, O);
  k_proj      <<<512,  256, 0, stream>>>(O, wot, out);
}

// Round 13
// 178.883 us; speedup vs baseline: 1.3956x; 1.1577x over previous
//
#include <hip/hip_runtime.h>

// Partitioned MHA: x(4,2048,1024) fp32 -> (out_c, out_p) each (4,2048,512) fp32.
// R13: R12's fragment-major A-operands with the stride bug fixed: per
// (tile,part,ks) block = 16 rows x 32 k = 512 u16 -> row stride 32 (R12 used
// 64 -> overlapping blocks -> write races, absmax 3e-2). All three sites
// fixed (k_cvt_x, k_qkv, OA epilogue + k_proj). Pure permutation — absmax
// must return to exactly 1.2207e-4. k_attn hot loop untouched (R9-verified).

typedef __attribute__((ext_vector_type(8))) short bf16x8;
typedef __attribute__((ext_vector_type(4))) float f32x4;
typedef unsigned short u16;

#define QSCALE 0.18033688011112042f  // (1/sqrt(64)) * log2(e): max-free softmax uses exp2(s)

__device__ __forceinline__ u16 f2bf(float f){
  unsigned u = __builtin_bit_cast(unsigned, f);
  u += 0x7FFFu + ((u >> 16) & 1u);
  return (u16)(u >> 16);
}

__device__ __forceinline__ unsigned cvtpk(float lo, float hi){
  unsigned r;
  asm("v_cvt_pk_bf16_f32 %0, %1, %2" : "=v"(r) : "v"(lo), "v"(hi));
  return r;
}

__device__ __forceinline__ void gload16(const void* g, void* l){
  __builtin_amdgcn_global_load_lds(
    (const __attribute__((address_space(1))) unsigned*)g,
    (__attribute__((address_space(3))) unsigned*)l, 16, 0, 0);
}

// ---------- x fp32 -> bf16, A-fragment-major ----------
// xA[((tile*2+part)*16+ks)*512 + li*32 + lg*8 + e]  (tile=row>>4, li=row&15,
// part=col>>9, ks=(col>>5)&15, lg=(col>>3)&3, e=col&7) — bijective 16x32 block.
__global__ __launch_bounds__(256) void k_cvt_x(const float4* __restrict__ x, u16* __restrict__ xA){
  unsigned i = blockIdx.x*256 + threadIdx.x;
  float4 v = x[i];
  unsigned j = i*4;
  unsigned row = j >> 10, col = j & 1023u;
  unsigned tile = row >> 4, li = row & 15u;
  unsigned part = col >> 9, ks = (col >> 5) & 15u, lg = (col >> 3) & 3u, e = col & 7u;
  uint2 pk;
  pk.x = (unsigned)f2bf(v.x) | ((unsigned)f2bf(v.y) << 16);
  pk.y = (unsigned)f2bf(v.z) | ((unsigned)f2bf(v.w) << 16);
  *(uint2*)(xA + (size_t)(((tile*2 + part)*16 + ks)*512) + li*32 + lg*8 + e) = pk;
}

// ---------- repack w_qkv -> FRAGMENT-MAJOR wt[ph][ks(16)][n(6)][lane(64)][8] bf16 ----------
__global__ __launch_bounds__(256) void k_repack_qkv(const float* __restrict__ wc, const float* __restrict__ wp,
                                                    u16* __restrict__ wt){
  unsigned i = blockIdx.x*256 + threadIdx.x;      // 1,572,864 total
  unsigned ph = i / 49152u;
  unsigned r  = i - ph*49152u;
  unsigned ks = r / 3072u;
  unsigned r2 = r - ks*3072u;
  unsigned n  = r2 >> 9;
  unsigned r3 = r2 & 511u;
  unsigned lg = r3 >> 7, li = (r3 >> 3) & 15u, e = r3 & 7u;
  unsigned h = ph & 15u;
  unsigned f = ks*32u + lg*8u + e;
  const float* src = (ph < 16) ? wc : wp;
  wt[i] = f2bf(src[h*49152u + f*96u + (n>>1)*32u + (n&1u)*16u + li]);
}

// ---------- repack w_o -> FRAGMENT-MAJOR wot[part][ft(4)][ks(16)][n(8)][lane(64)][8] ----------
__global__ __launch_bounds__(256) void k_repack_wo(const float* __restrict__ wc, const float* __restrict__ wp,
                                                   u16* __restrict__ wt){
  unsigned i = blockIdx.x*256 + threadIdx.x;      // 524,288 total
  unsigned e = i & 7u;
  unsigned lane = (i >> 3) & 63u;
  unsigned n  = (i >> 9) & 7u;
  unsigned ks = (i >> 12) & 15u;
  unsigned ft = (i >> 16) & 3u;
  unsigned part = i >> 18;
  unsigned f = ft*128u + n*16u + (lane & 15u);
  unsigned a = (lane >> 4)*8u + e;
  const float* src = part ? wp : wc;
  wt[i] = f2bf(src[ks*16384u + a*512u + f]);
}

// ---------- QKV projection: 256-token blocks, wave owns 64 rows (XCD-affine) ----------
__global__ __launch_bounds__(256) void k_qkv(const u16* __restrict__ xA, const u16* __restrict__ wt,
                                             u16* __restrict__ Q, u16* __restrict__ K, u16* __restrict__ VT){
  const int lane = threadIdx.x & 63, wv = threadIdx.x >> 6;
  const int lg = lane >> 4, li = lane & 15;
  const int blk = blockIdx.x;
  const int xcd = blk & 7, idx = blk >> 3;
  const int tt  = (idx >> 5)*8 + xcd;
  const int ph  = idx & 31;
  const int row0 = tt*256 + wv*64;
  const int part = ph >> 4, h = ph & 15;

  f32x4 acc[4][6] = {};
  const u16* wbase = wt + (size_t)ph*49152;
  const unsigned aoff = (unsigned)(li*32 + lg*8);
  #pragma unroll 2
  for (int ks = 0; ks < 16; ++ks){
    bf16x8 a[4], b[6];
    #pragma unroll
    for (int m=0;m<4;++m)
      a[m] = *(const bf16x8*)(xA + (size_t)(((tt*16 + wv*4 + m)*2 + part)*16 + ks)*512 + aoff);
    #pragma unroll
    for (int n=0;n<6;++n)
      b[n] = *(const bf16x8*)(wbase + ks*3072 + n*512 + lane*8);
    #pragma unroll
    for (int m=0;m<4;++m)
      #pragma unroll
      for (int n=0;n<6;++n)
        acc[m][n] = __builtin_amdgcn_mfma_f32_16x16x32_bf16(a[m], b[n], acc[m][n], 0, 0, 0);
  }

  const int b_ = row0 >> 11;
  const int bh = b_*16 + h;
  const int tl0 = (row0 & 2047) + lg*4;
  #pragma unroll
  for (int m=0;m<4;++m){
    #pragma unroll
    for (int n=0;n<6;++n){
      const int c = n >> 1;
      const int af = part*32 + (n & 1)*16 + li;
      if (c == 2){
        uint2 pk;
        pk.x = (unsigned)f2bf(acc[m][n][0]) | ((unsigned)f2bf(acc[m][n][1]) << 16);
        pk.y = (unsigned)f2bf(acc[m][n][2]) | ((unsigned)f2bf(acc[m][n][3]) << 16);
        *(uint2*)(VT + (size_t)(bh*64 + af)*2048 + tl0 + m*16) = pk;
      } else {
        u16* dst = (c == 0) ? Q : K;
        const float sc = (c == 0) ? QSCALE : 1.0f;
        #pragma unroll
        for (int r=0;r<4;++r){
          int tl = tl0 + m*16 + r;
          dst[((size_t)bh*2048 + tl)*64 + af] = f2bf(acc[m][n][r] * sc);
        }
      }
    }
  }
}

// ---------- flash attention (R9-verified hot loop; OA-layout epilogue) ----------
// grid 1024 (XCD-swizzled). 4 waves * 32 q-rows. KV tile = 32 keys.
// LDS: K0@0 K1@4096 | V0@8192 V1@12288 | P 4x2x[32][40] u16 @16384. 36864 B.
#define NKT 64
#define PLD 40
__global__ __launch_bounds__(256, 4) void k_attn(const u16* __restrict__ Q, const u16* __restrict__ K,
                                                 const u16* __restrict__ VT, u16* __restrict__ OA){
  __shared__ __align__(16) char smem[36864];
  const int lane = threadIdx.x & 63, w = threadIdx.x >> 6;
  const int lg = lane >> 4, li = lane & 15;
  const int swz = (blockIdx.x & 7)*128 + (blockIdx.x >> 3);   // XCD-contiguous
  const int bh = swz >> 4, qt = swz & 15;
  const int q0 = qt*128 + w*32;

  const char* Kg = (const char*)(K  + (size_t)bh*131072);
  const char* Vg = (const char*)(VT + (size_t)bh*131072);
  const u16*  Qb = Q + (size_t)bh*131072;
  u16* pw = (u16*)(smem + 16384) + w*2560;      // + copy*1280 (u16 units)

  const unsigned ksrc = (unsigned)((w*8 + (lane>>3))*128 + (((lane&7) ^ (lane>>3)) << 4));
  const unsigned vsrc0 = (unsigned)((w*16 + (lane>>2))*4096 + (((lane&3) ^ ((lane>>2)&3)) << 4));
  const unsigned ldst = (unsigned)(w*1024);

  const unsigned kc0 = (unsigned)(((     lg) ^ (li&7)) << 4);
  const unsigned kc1 = (unsigned)(((4 +  lg) ^ (li&7)) << 4);
  const unsigned vc  = (unsigned)(((lg) ^ (li&3)) << 4);

  bf16x8 aq[2][2];
  #pragma unroll
  for (int m=0;m<2;++m)
    #pragma unroll
    for (int kd=0;kd<2;++kd)
      aq[m][kd] = *(const bf16x8*)(Qb + (size_t)(q0 + m*16 + li)*64 + kd*32 + lg*8);

  const short one_bf = (short)0x3F80;
  bf16x8 ones = {one_bf,one_bf,one_bf,one_bf,one_bf,one_bf,one_bf,one_bf};

  f32x4 o[2][4] = {};
  f32x4 ls[2] = {};

  auto QKEXP = [&](const char* sK, u16* pW){
    #pragma unroll
    for (int n=0;n<2;++n){
      bf16x8 bk0 = *(const bf16x8*)(sK + (n*16 + li)*128 + kc0);
      bf16x8 bk1 = *(const bf16x8*)(sK + (n*16 + li)*128 + kc1);
      #pragma unroll
      for (int m=0;m<2;++m){
        f32x4 s = {0.f,0.f,0.f,0.f};   // S^T: row k=n*16+4lg+r, col q=m*16+li
        s = __builtin_amdgcn_mfma_f32_16x16x32_bf16(bk0, aq[m][0], s, 0, 0, 0);
        s = __builtin_amdgcn_mfma_f32_16x16x32_bf16(bk1, aq[m][1], s, 0, 0, 0);
        uint2 pk;
        pk.x = cvtpk(__builtin_exp2f(s[0]), __builtin_exp2f(s[1]));
        pk.y = cvtpk(__builtin_exp2f(s[2]), __builtin_exp2f(s[3]));
        *(uint2*)(pW + (size_t)(m*16 + li)*PLD + n*16 + lg*4) = pk;
      }
    }
  };
  auto PV = [&](const char* sV, const u16* pR){
    bf16x8 pa0 = *(const bf16x8*)(pR + (size_t)(     li)*PLD + lg*8);
    bf16x8 pa1 = *(const bf16x8*)(pR + (size_t)(16 + li)*PLD + lg*8);
    __builtin_amdgcn_s_setprio(1);
    #pragma unroll
    for (int nd=0;nd<4;++nd){
      bf16x8 bv = *(const bf16x8*)(sV + (nd*16 + li)*64 + vc);
      o[0][nd] = __builtin_amdgcn_mfma_f32_16x16x32_bf16(pa0, bv, o[0][nd], 0, 0, 0);
      o[1][nd] = __builtin_amdgcn_mfma_f32_16x16x32_bf16(pa1, bv, o[1][nd], 0, 0, 0);
    }
    ls[0] = __builtin_amdgcn_mfma_f32_16x16x32_bf16(pa0, ones, ls[0], 0, 0, 0);
    ls[1] = __builtin_amdgcn_mfma_f32_16x16x32_bf16(pa1, ones, ls[1], 0, 0, 0);
    __builtin_amdgcn_s_setprio(0);
  };

  // prologue: stage K0,V0,K1; drain; barrier; P(0) -> pbuf0; barrier
  gload16(Kg + ksrc,          smem + ldst);
  gload16(Vg + vsrc0,         smem + 8192 + ldst);
  gload16(Kg + 4096u + ksrc,  smem + 4096 + ldst);
  asm volatile("s_waitcnt vmcnt(0)" ::: "memory");
  __builtin_amdgcn_s_barrier();
  QKEXP(smem, pw);                       // P(0) into copy 0
  __builtin_amdgcn_s_barrier();

  for (int kt = 0; kt < NKT-1; ++kt){
    const int pr = kt & 1, pn = pr ^ 1;
    gload16(Vg + (kt+1)*64u + vsrc0, smem + 8192 + pn*4096 + ldst);
    if (kt + 2 < NKT)
      gload16(Kg + (kt+2)*4096u + ksrc, smem + pr*4096 + ldst);
    QKEXP(smem + pn*4096, pw + pn*1280);
    PV(smem + 8192 + pr*4096, pw + pr*1280);
    asm volatile("s_waitcnt vmcnt(0)" ::: "memory");
    __builtin_amdgcn_s_barrier();
  }
  PV(smem + 8192 + ((NKT-1)&1)*4096, pw + ((NKT-1)&1)*1280);   // PV(63)

  // store O in OA layout: OA[((tile*16+h)*2+part)*512 + li'*32 + lg'*8 + e']
  // tile = (b*2048 + q0 + m*16)>>4, li' = lg*4+r, part = nd>>1,
  // lg' = (nd&1)*2 + (li>>3), e' = li&7.
  const int b_ = bh >> 4, h = bh & 15;
  #pragma unroll
  for (int m=0;m<2;++m){
    const int tile = (b_*2048 + q0 + m*16) >> 4;
    #pragma unroll
    for (int r=0;r<4;++r){
      float linv = 1.0f / ls[m][r];
      #pragma unroll
      for (int nd=0;nd<4;++nd){
        OA[(size_t)(((tile*16 + h)*2 + (nd>>1))*512)
           + (lg*4 + r)*32 + ((nd&1)*2 + (li>>3))*8 + (li&7)] = f2bf(o[m][nd][r] * linv);
      }
    }
  }
}

// ---------- output projection (XCD-affine; fragment-major weights + OA) ----------
__global__ __launch_bounds__(256) void k_proj(const u16* __restrict__ OA, const u16* __restrict__ wot,
                                              float* __restrict__ out){
  const int lane = threadIdx.x & 63, wv = threadIdx.x >> 6;
  const int lg = lane >> 4, li = lane & 15;
  const int blk = blockIdx.x;
  const int xcd = blk & 7, idx = blk >> 3;
  const int rowTile = (idx >> 3)*8 + xcd;
  const int colTile = idx & 7;
  const int row0 = rowTile*128 + wv*32;
  const int part = colTile >> 2;
  const int ft   = colTile & 3;
  const int f0   = ft*128;

  f32x4 acc[2][8] = {};
  const u16* wbase = wot + (size_t)part*262144 + (size_t)ft*65536;
  const unsigned aoff = (unsigned)(li*32 + lg*8);
  #pragma unroll 4
  for (int ks = 0; ks < 16; ++ks){
    bf16x8 a[2];
    #pragma unroll
    for (int m=0;m<2;++m)
      a[m] = *(const bf16x8*)(OA + (size_t)((((rowTile*8 + wv*2 + m)*16 + ks)*2 + part)*512) + aoff);
    #pragma unroll
    for (int n=0;n<8;++n){
      bf16x8 b = *(const bf16x8*)(wbase + ks*4096 + n*512 + lane*8);
      #pragma unroll
      for (int m=0;m<2;++m)
        acc[m][n] = __builtin_amdgcn_mfma_f32_16x16x32_bf16(a[m], b, acc[m][n], 0, 0, 0);
    }
  }
  float* obp = out + (size_t)part*(8192u*512u);
  #pragma unroll
  for (int m=0;m<2;++m)
    #pragma unroll
    for (int n=0;n<8;++n)
      #pragma unroll
      for (int r=0;r<4;++r)
        obp[(size_t)(row0 + m*16 + lg*4 + r)*512 + f0 + n*16 + li] = acc[m][n][r];
}

extern "C" void kernel_launch(void* const* d_in, const int* in_sizes, int n_in,
                              void* d_out, int out_size, void* d_ws, size_t ws_size,
                              hipStream_t stream){
  const float* x   = (const float*)d_in[0];
  const float* wqc = (const float*)d_in[1];
  const float* wqp = (const float*)d_in[2];
  const float* woc = (const float*)d_in[3];
  const float* wop = (const float*)d_in[4];

  char* ws = (char*)d_ws;
  u16* xA  = (u16*)(ws);
  u16* Q   = (u16*)(ws + 16777216);
  u16* K   = (u16*)(ws + 2*16777216);
  u16* VT  = (u16*)(ws + 3*16777216);
  u16* wqt = (u16*)(ws + 4*16777216);
  u16* wot = (u16*)(ws + 4*16777216 + 3145728);
  u16* OA  = xA;   // xA dead after k_qkv
  float* out = (float*)d_out;

  k_cvt_x     <<<8192, 256, 0, stream>>>((const float4*)x, xA);
  k_repack_qkv<<<6144, 256, 0, stream>>>(wqc, wqp, wqt);
  k_repack_wo <<<2048, 256, 0, stream>>>(woc, wop, wot);
  k_qkv       <<<1024, 256, 0, stream>>>(xA, wqt, Q, K, VT);
  k_attn      <<<1024, 256, 0, stream>>>(Q, K, VT, OA);
  k_proj      <<<512,  256, 0, stream>>>(OA, wot, out);
}

// Round 14
// 174.204 us; speedup vs baseline: 1.4331x; 1.0269x over previous
//
#include <hip/hip_runtime.h>

// Partitioned MHA: x(4,2048,1024) fp32 -> (out_c, out_p) each (4,2048,512) fp32.
// R14: (a) V stored as pre-swizzled per-KV-tile 4KB images (VTg[bh][kt][d64x
// 64B rows, chunk^=(d&3)]) so k_attn V-staging gload is 1KB contiguous/instr
// (was 16 rows x 4096B stride = 16 transactions); LDS dest & read swizzle
// unchanged. (b) cvt_x+repacks fused into one k_prep kernel (6->4 launches).
// Pure permutations — absmax must stay exactly 1.2207e-4. Hot loops frozen.

typedef __attribute__((ext_vector_type(8))) short bf16x8;
typedef __attribute__((ext_vector_type(4))) float f32x4;
typedef unsigned short u16;

#define QSCALE 0.18033688011112042f  // (1/sqrt(64)) * log2(e): max-free softmax uses exp2(s)

__device__ __forceinline__ u16 f2bf(float f){
  unsigned u = __builtin_bit_cast(unsigned, f);
  u += 0x7FFFu + ((u >> 16) & 1u);
  return (u16)(u >> 16);
}

__device__ __forceinline__ unsigned cvtpk(float lo, float hi){
  unsigned r;
  asm("v_cvt_pk_bf16_f32 %0, %1, %2" : "=v"(r) : "v"(lo), "v"(hi));
  return r;
}

__device__ __forceinline__ void gload16(const void* g, void* l){
  __builtin_amdgcn_global_load_lds(
    (const __attribute__((address_space(1))) unsigned*)g,
    (__attribute__((address_space(3))) unsigned*)l, 16, 0, 0);
}

// ---------- fused prologue: cvt_x (blk<8192) | repack_qkv (<14336) | repack_wo ----------
__global__ __launch_bounds__(256) void k_prep(const float4* __restrict__ x, u16* __restrict__ xA,
                                              const float* __restrict__ wqc, const float* __restrict__ wqp,
                                              u16* __restrict__ wqt,
                                              const float* __restrict__ woc, const float* __restrict__ wop,
                                              u16* __restrict__ wot){
  const unsigned blk = blockIdx.x;
  if (blk < 8192u){
    // x fp32 -> bf16, A-fragment-major: xA[((tile*2+part)*16+ks)*512 + li*32+lg*8+e]
    unsigned i = blk*256 + threadIdx.x;
    float4 v = x[i];
    unsigned j = i*4;
    unsigned row = j >> 10, col = j & 1023u;
    unsigned tile = row >> 4, li = row & 15u;
    unsigned part = col >> 9, ks = (col >> 5) & 15u, lg = (col >> 3) & 3u, e = col & 7u;
    uint2 pk;
    pk.x = (unsigned)f2bf(v.x) | ((unsigned)f2bf(v.y) << 16);
    pk.y = (unsigned)f2bf(v.z) | ((unsigned)f2bf(v.w) << 16);
    *(uint2*)(xA + (size_t)(((tile*2 + part)*16 + ks)*512) + li*32 + lg*8 + e) = pk;
  } else if (blk < 14336u){
    // w_qkv -> fragment-major wt[ph][ks][n][lane][8]
    unsigned i = (blk - 8192u)*256 + threadIdx.x;
    unsigned ph = i / 49152u;
    unsigned r  = i - ph*49152u;
    unsigned ks = r / 3072u;
    unsigned r2 = r - ks*3072u;
    unsigned n  = r2 >> 9;
    unsigned r3 = r2 & 511u;
    unsigned lg = r3 >> 7, li = (r3 >> 3) & 15u, e = r3 & 7u;
    unsigned h = ph & 15u;
    unsigned f = ks*32u + lg*8u + e;
    const float* src = (ph < 16) ? wqc : wqp;
    wqt[i] = f2bf(src[h*49152u + f*96u + (n>>1)*32u + (n&1u)*16u + li]);
  } else {
    // w_o -> fragment-major wot[part][ft][ks][n][lane][8]
    unsigned i = (blk - 14336u)*256 + threadIdx.x;
    unsigned e = i & 7u;
    unsigned lane = (i >> 3) & 63u;
    unsigned n  = (i >> 9) & 7u;
    unsigned ks = (i >> 12) & 15u;
    unsigned ft = (i >> 16) & 3u;
    unsigned part = i >> 18;
    unsigned f = ft*128u + n*16u + (lane & 15u);
    unsigned a = (lane >> 4)*8u + e;
    const float* src = part ? wop : woc;
    wot[i] = f2bf(src[ks*16384u + a*512u + f]);
  }
}

// ---------- QKV projection: 256-token blocks, wave owns 64 rows (XCD-affine) ----------
// Q,K: [bh][2048][64] bf16 (Q pre-scaled). V: VTg[bh][kt 64][4KB tile],
// tile byte = d*64 + ((c ^ (d&3))<<4) + (k&7)*2, c = k>>3 (pre-swizzled LDS image).
__global__ __launch_bounds__(256) void k_qkv(const u16* __restrict__ xA, const u16* __restrict__ wt,
                                             u16* __restrict__ Q, u16* __restrict__ K, u16* __restrict__ VT){
  const int lane = threadIdx.x & 63, wv = threadIdx.x >> 6;
  const int lg = lane >> 4, li = lane & 15;
  const int blk = blockIdx.x;
  const int xcd = blk & 7, idx = blk >> 3;
  const int tt  = (idx >> 5)*8 + xcd;
  const int ph  = idx & 31;
  const int row0 = tt*256 + wv*64;
  const int part = ph >> 4, h = ph & 15;

  f32x4 acc[4][6] = {};
  const u16* wbase = wt + (size_t)ph*49152;
  const unsigned aoff = (unsigned)(li*32 + lg*8);
  #pragma unroll 2
  for (int ks = 0; ks < 16; ++ks){
    bf16x8 a[4], b[6];
    #pragma unroll
    for (int m=0;m<4;++m)
      a[m] = *(const bf16x8*)(xA + (size_t)(((tt*16 + wv*4 + m)*2 + part)*16 + ks)*512 + aoff);
    #pragma unroll
    for (int n=0;n<6;++n)
      b[n] = *(const bf16x8*)(wbase + ks*3072 + n*512 + lane*8);
    #pragma unroll
    for (int m=0;m<4;++m)
      #pragma unroll
      for (int n=0;n<6;++n)
        acc[m][n] = __builtin_amdgcn_mfma_f32_16x16x32_bf16(a[m], b[n], acc[m][n], 0, 0, 0);
  }

  const int b_ = row0 >> 11;
  const int bh = b_*16 + h;
  const int tl0 = (row0 & 2047) + lg*4;
  #pragma unroll
  for (int m=0;m<4;++m){
    #pragma unroll
    for (int n=0;n<6;++n){
      const int c = n >> 1;
      const int af = part*32 + (n & 1)*16 + li;
      if (c == 2){
        uint2 pk;
        pk.x = (unsigned)f2bf(acc[m][n][0]) | ((unsigned)f2bf(acc[m][n][1]) << 16);
        pk.y = (unsigned)f2bf(acc[m][n][2]) | ((unsigned)f2bf(acc[m][n][3]) << 16);
        // V tile image: kt = ((row0&2047)>>5)+(m>>1); kk=(m&1)*16+lg*4+r;
        // chunk c2 = kk>>3 = (m&1)*2+(lg>>1); byte = af*64+((c2^(af&3))<<4)+(lg&1)*8
        const int c2 = (m&1)*2 + (lg>>1);
        char* dst = (char*)VT + (size_t)bh*262144
                  + (size_t)(((row0 & 2047) >> 5) + (m>>1))*4096
                  + af*64 + ((c2 ^ (af&3))<<4) + (lg&1)*8;
        *(uint2*)dst = pk;
      } else {
        u16* dst = (c == 0) ? Q : K;
        const float sc = (c == 0) ? QSCALE : 1.0f;
        #pragma unroll
        for (int r=0;r<4;++r){
          int tl = tl0 + m*16 + r;
          dst[((size_t)bh*2048 + tl)*64 + af] = f2bf(acc[m][n][r] * sc);
        }
      }
    }
  }
}

// ---------- flash attention (R9-verified hot loop; linear V staging) ----------
// grid 1024 (XCD-swizzled). 4 waves * 32 q-rows. KV tile = 32 keys.
// LDS: K0@0 K1@4096 | V0@8192 V1@12288 | P 4x2x[32][40] u16 @16384. 36864 B.
#define NKT 64
#define PLD 40
__global__ __launch_bounds__(256, 4) void k_attn(const u16* __restrict__ Q, const u16* __restrict__ K,
                                                 const u16* __restrict__ VT, u16* __restrict__ OA){
  __shared__ __align__(16) char smem[36864];
  const int lane = threadIdx.x & 63, w = threadIdx.x >> 6;
  const int lg = lane >> 4, li = lane & 15;
  const int swz = (blockIdx.x & 7)*128 + (blockIdx.x >> 3);   // XCD-contiguous
  const int bh = swz >> 4, qt = swz & 15;
  const int q0 = qt*128 + w*32;

  const char* Kg = (const char*)(K + (size_t)bh*131072);
  const char* Vg = (const char*)VT + (size_t)bh*262144;
  const u16*  Qb = Q + (size_t)bh*131072;
  u16* pw = (u16*)(smem + 16384) + w*2560;      // + copy*1280 (u16 units)

  const unsigned ksrc = (unsigned)((w*8 + (lane>>3))*128 + (((lane&7) ^ (lane>>3)) << 4));
  const unsigned vsrc = (unsigned)(w*1024 + lane*16);   // linear: tile is LDS image
  const unsigned ldst = (unsigned)(w*1024);

  const unsigned kc0 = (unsigned)(((     lg) ^ (li&7)) << 4);
  const unsigned kc1 = (unsigned)(((4 +  lg) ^ (li&7)) << 4);
  const unsigned vc  = (unsigned)(((lg) ^ (li&3)) << 4);

  bf16x8 aq[2][2];
  #pragma unroll
  for (int m=0;m<2;++m)
    #pragma unroll
    for (int kd=0;kd<2;++kd)
      aq[m][kd] = *(const bf16x8*)(Qb + (size_t)(q0 + m*16 + li)*64 + kd*32 + lg*8);

  const short one_bf = (short)0x3F80;
  bf16x8 ones = {one_bf,one_bf,one_bf,one_bf,one_bf,one_bf,one_bf,one_bf};

  f32x4 o[2][4] = {};
  f32x4 ls[2] = {};

  auto QKEXP = [&](const char* sK, u16* pW){
    #pragma unroll
    for (int n=0;n<2;++n){
      bf16x8 bk0 = *(const bf16x8*)(sK + (n*16 + li)*128 + kc0);
      bf16x8 bk1 = *(const bf16x8*)(sK + (n*16 + li)*128 + kc1);
      #pragma unroll
      for (int m=0;m<2;++m){
        f32x4 s = {0.f,0.f,0.f,0.f};   // S^T: row k=n*16+4lg+r, col q=m*16+li
        s = __builtin_amdgcn_mfma_f32_16x16x32_bf16(bk0, aq[m][0], s, 0, 0, 0);
        s = __builtin_amdgcn_mfma_f32_16x16x32_bf16(bk1, aq[m][1], s, 0, 0, 0);
        uint2 pk;
        pk.x = cvtpk(__builtin_exp2f(s[0]), __builtin_exp2f(s[1]));
        pk.y = cvtpk(__builtin_exp2f(s[2]), __builtin_exp2f(s[3]));
        *(uint2*)(pW + (size_t)(m*16 + li)*PLD + n*16 + lg*4) = pk;
      }
    }
  };
  auto PV = [&](const char* sV, const u16* pR){
    bf16x8 pa0 = *(const bf16x8*)(pR + (size_t)(     li)*PLD + lg*8);
    bf16x8 pa1 = *(const bf16x8*)(pR + (size_t)(16 + li)*PLD + lg*8);
    __builtin_amdgcn_s_setprio(1);
    #pragma unroll
    for (int nd=0;nd<4;++nd){
      bf16x8 bv = *(const bf16x8*)(sV + (nd*16 + li)*64 + vc);
      o[0][nd] = __builtin_amdgcn_mfma_f32_16x16x32_bf16(pa0, bv, o[0][nd], 0, 0, 0);
      o[1][nd] = __builtin_amdgcn_mfma_f32_16x16x32_bf16(pa1, bv, o[1][nd], 0, 0, 0);
    }
    ls[0] = __builtin_amdgcn_mfma_f32_16x16x32_bf16(pa0, ones, ls[0], 0, 0, 0);
    ls[1] = __builtin_amdgcn_mfma_f32_16x16x32_bf16(pa1, ones, ls[1], 0, 0, 0);
    __builtin_amdgcn_s_setprio(0);
  };

  // prologue: stage K0,V0,K1; drain; barrier; P(0) -> pbuf0; barrier
  gload16(Kg + ksrc,          smem + ldst);
  gload16(Vg + vsrc,          smem + 8192 + ldst);
  gload16(Kg + 4096u + ksrc,  smem + 4096 + ldst);
  asm volatile("s_waitcnt vmcnt(0)" ::: "memory");
  __builtin_amdgcn_s_barrier();
  QKEXP(smem, pw);                       // P(0) into copy 0
  __builtin_amdgcn_s_barrier();

  for (int kt = 0; kt < NKT-1; ++kt){
    const int pr = kt & 1, pn = pr ^ 1;
    gload16(Vg + (kt+1)*4096u + vsrc, smem + 8192 + pn*4096 + ldst);
    if (kt + 2 < NKT)
      gload16(Kg + (kt+2)*4096u + ksrc, smem + pr*4096 + ldst);
    QKEXP(smem + pn*4096, pw + pn*1280);
    PV(smem + 8192 + pr*4096, pw + pr*1280);
    asm volatile("s_waitcnt vmcnt(0)" ::: "memory");
    __builtin_amdgcn_s_barrier();
  }
  PV(smem + 8192 + ((NKT-1)&1)*4096, pw + ((NKT-1)&1)*1280);   // PV(63)

  // store O in OA layout: OA[((tile*16+h)*2+part)*512 + li'*32 + lg'*8 + e']
  const int b_ = bh >> 4, h = bh & 15;
  #pragma unroll
  for (int m=0;m<2;++m){
    const int tile = (b_*2048 + q0 + m*16) >> 4;
    #pragma unroll
    for (int r=0;r<4;++r){
      float linv = 1.0f / ls[m][r];
      #pragma unroll
      for (int nd=0;nd<4;++nd){
        OA[(size_t)(((tile*16 + h)*2 + (nd>>1))*512)
           + (lg*4 + r)*32 + ((nd&1)*2 + (li>>3))*8 + (li&7)] = f2bf(o[m][nd][r] * linv);
      }
    }
  }
}

// ---------- output projection (XCD-affine; fragment-major weights + OA) ----------
__global__ __launch_bounds__(256) void k_proj(const u16* __restrict__ OA, const u16* __restrict__ wot,
                                              float* __restrict__ out){
  const int lane = threadIdx.x & 63, wv = threadIdx.x >> 6;
  const int lg = lane >> 4, li = lane & 15;
  const int blk = blockIdx.x;
  const int xcd = blk & 7, idx = blk >> 3;
  const int rowTile = (idx >> 3)*8 + xcd;
  const int colTile = idx & 7;
  const int row0 = rowTile*128 + wv*32;
  const int part = colTile >> 2;
  const int ft   = colTile & 3;
  const int f0   = ft*128;

  f32x4 acc[2][8] = {};
  const u16* wbase = wot + (size_t)part*262144 + (size_t)ft*65536;
  const unsigned aoff = (unsigned)(li*32 + lg*8);
  #pragma unroll 4
  for (int ks = 0; ks < 16; ++ks){
    bf16x8 a[2];
    #pragma unroll
    for (int m=0;m<2;++m)
      a[m] = *(const bf16x8*)(OA + (size_t)((((rowTile*8 + wv*2 + m)*16 + ks)*2 + part)*512) + aoff);
    #pragma unroll
    for (int n=0;n<8;++n){
      bf16x8 b = *(const bf16x8*)(wbase + ks*4096 + n*512 + lane*8);
      #pragma unroll
      for (int m=0;m<2;++m)
        acc[m][n] = __builtin_amdgcn_mfma_f32_16x16x32_bf16(a[m], b, acc[m][n], 0, 0, 0);
    }
  }
  float* obp = out + (size_t)part*(8192u*512u);
  #pragma unroll
  for (int m=0;m<2;++m)
    #pragma unroll
    for (int n=0;n<8;++n)
      #pragma unroll
      for (int r=0;r<4;++r)
        obp[(size_t)(row0 + m*16 + lg*4 + r)*512 + f0 + n*16 + li] = acc[m][n][r];
}

extern "C" void kernel_launch(void* const* d_in, const int* in_sizes, int n_in,
                              void* d_out, int out_size, void* d_ws, size_t ws_size,
                              hipStream_t stream){
  const float* x   = (const float*)d_in[0];
  const float* wqc = (const float*)d_in[1];
  const float* wqp = (const float*)d_in[2];
  const float* woc = (const float*)d_in[3];
  const float* wop = (const float*)d_in[4];

  char* ws = (char*)d_ws;
  u16* xA  = (u16*)(ws);
  u16* Q   = (u16*)(ws + 16777216);
  u16* K   = (u16*)(ws + 2*16777216);
  u16* VT  = (u16*)(ws + 3*16777216);
  u16* wqt = (u16*)(ws + 4*16777216);
  u16* wot = (u16*)(ws + 4*16777216 + 3145728);
  u16* OA  = xA;   // xA dead after k_qkv
  float* out = (float*)d_out;

  k_prep <<<16384, 256, 0, stream>>>((const float4*)x, xA, wqc, wqp, wqt, woc, wop, wot);
  k_qkv  <<<1024,  256, 0, stream>>>(xA, wqt, Q, K, VT);
  k_attn <<<1024,  256, 0, stream>>>(Q, K, VT, OA);
  k_proj <<<512,   256, 0, stream>>>(OA, wot, out);
}

// Round 15
// 171.319 us; speedup vs baseline: 1.4572x; 1.0168x over previous
//
#include <hip/hip_runtime.h>

// Partitioned MHA: x(4,2048,1024) fp32 -> (out_c, out_p) each (4,2048,512) fp32.
// R15: K bypasses LDS. k_qkv stores K as per-tile fragment images
// Kfrag[bh][kt32][n][half][lane][8]; k_attn loads them straight to registers
// (1KB contiguous per instr, double-banked ka0/ka1 two tiles ahead, unroll-2
// so bank index is compile-time). Kills 4 dup ds_reads/wave-iter + K LDS-write
// + K LDS bufs (36.9->28.7KB). V/P/math bit-identical (absmax 1.2207e-4).

typedef __attribute__((ext_vector_type(8))) short bf16x8;
typedef __attribute__((ext_vector_type(4))) float f32x4;
typedef unsigned short u16;

#define QSCALE 0.18033688011112042f  // (1/sqrt(64)) * log2(e): max-free softmax uses exp2(s)

__device__ __forceinline__ u16 f2bf(float f){
  unsigned u = __builtin_bit_cast(unsigned, f);
  u += 0x7FFFu + ((u >> 16) & 1u);
  return (u16)(u >> 16);
}

__device__ __forceinline__ unsigned cvtpk(float lo, float hi){
  unsigned r;
  asm("v_cvt_pk_bf16_f32 %0, %1, %2" : "=v"(r) : "v"(lo), "v"(hi));
  return r;
}

__device__ __forceinline__ void gload16(const void* g, void* l){
  __builtin_amdgcn_global_load_lds(
    (const __attribute__((address_space(1))) unsigned*)g,
    (__attribute__((address_space(3))) unsigned*)l, 16, 0, 0);
}

// ---------- fused prologue: cvt_x (blk<8192) | repack_qkv (<14336) | repack_wo ----------
__global__ __launch_bounds__(256) void k_prep(const float4* __restrict__ x, u16* __restrict__ xA,
                                              const float* __restrict__ wqc, const float* __restrict__ wqp,
                                              u16* __restrict__ wqt,
                                              const float* __restrict__ woc, const float* __restrict__ wop,
                                              u16* __restrict__ wot){
  const unsigned blk = blockIdx.x;
  if (blk < 8192u){
    unsigned i = blk*256 + threadIdx.x;
    float4 v = x[i];
    unsigned j = i*4;
    unsigned row = j >> 10, col = j & 1023u;
    unsigned tile = row >> 4, li = row & 15u;
    unsigned part = col >> 9, ks = (col >> 5) & 15u, lg = (col >> 3) & 3u, e = col & 7u;
    uint2 pk;
    pk.x = (unsigned)f2bf(v.x) | ((unsigned)f2bf(v.y) << 16);
    pk.y = (unsigned)f2bf(v.z) | ((unsigned)f2bf(v.w) << 16);
    *(uint2*)(xA + (size_t)(((tile*2 + part)*16 + ks)*512) + li*32 + lg*8 + e) = pk;
  } else if (blk < 14336u){
    unsigned i = (blk - 8192u)*256 + threadIdx.x;
    unsigned ph = i / 49152u;
    unsigned r  = i - ph*49152u;
    unsigned ks = r / 3072u;
    unsigned r2 = r - ks*3072u;
    unsigned n  = r2 >> 9;
    unsigned r3 = r2 & 511u;
    unsigned lg = r3 >> 7, li = (r3 >> 3) & 15u, e = r3 & 7u;
    unsigned h = ph & 15u;
    unsigned f = ks*32u + lg*8u + e;
    const float* src = (ph < 16) ? wqc : wqp;
    wqt[i] = f2bf(src[h*49152u + f*96u + (n>>1)*32u + (n&1u)*16u + li]);
  } else {
    unsigned i = (blk - 14336u)*256 + threadIdx.x;
    unsigned e = i & 7u;
    unsigned lane = (i >> 3) & 63u;
    unsigned n  = (i >> 9) & 7u;
    unsigned ks = (i >> 12) & 15u;
    unsigned ft = (i >> 16) & 3u;
    unsigned part = i >> 18;
    unsigned f = ft*128u + n*16u + (lane & 15u);
    unsigned a = (lane >> 4)*8u + e;
    const float* src = part ? wop : woc;
    wot[i] = f2bf(src[ks*16384u + a*512u + f]);
  }
}

// ---------- QKV projection (XCD-affine) ----------
// Q: [bh][2048][64] (pre-scaled). K: Kfrag[bh][kt 64][4KB]: u16 off =
// (t>>5)*2048+((t>>4)&1)*1024+(af>>5)*512+((af>>3)&3)*128+(t&15)*8+(af&7).
// V: per-tile LDS images (R14).
__global__ __launch_bounds__(256) void k_qkv(const u16* __restrict__ xA, const u16* __restrict__ wt,
                                             u16* __restrict__ Q, u16* __restrict__ K, u16* __restrict__ VT){
  const int lane = threadIdx.x & 63, wv = threadIdx.x >> 6;
  const int lg = lane >> 4, li = lane & 15;
  const int blk = blockIdx.x;
  const int xcd = blk & 7, idx = blk >> 3;
  const int tt  = (idx >> 5)*8 + xcd;
  const int ph  = idx & 31;
  const int row0 = tt*256 + wv*64;
  const int part = ph >> 4, h = ph & 15;

  f32x4 acc[4][6] = {};
  const u16* wbase = wt + (size_t)ph*49152;
  const unsigned aoff = (unsigned)(li*32 + lg*8);
  #pragma unroll 2
  for (int ks = 0; ks < 16; ++ks){
    bf16x8 a[4], b[6];
    #pragma unroll
    for (int m=0;m<4;++m)
      a[m] = *(const bf16x8*)(xA + (size_t)(((tt*16 + wv*4 + m)*2 + part)*16 + ks)*512 + aoff);
    #pragma unroll
    for (int n=0;n<6;++n)
      b[n] = *(const bf16x8*)(wbase + ks*3072 + n*512 + lane*8);
    #pragma unroll
    for (int m=0;m<4;++m)
      #pragma unroll
      for (int n=0;n<6;++n)
        acc[m][n] = __builtin_amdgcn_mfma_f32_16x16x32_bf16(a[m], b[n], acc[m][n], 0, 0, 0);
  }

  const int b_ = row0 >> 11;
  const int bh = b_*16 + h;
  const int tl0 = (row0 & 2047) + lg*4;
  #pragma unroll
  for (int m=0;m<4;++m){
    #pragma unroll
    for (int n=0;n<6;++n){
      const int c = n >> 1;
      const int af = part*32 + (n & 1)*16 + li;
      if (c == 2){
        uint2 pk;
        pk.x = (unsigned)f2bf(acc[m][n][0]) | ((unsigned)f2bf(acc[m][n][1]) << 16);
        pk.y = (unsigned)f2bf(acc[m][n][2]) | ((unsigned)f2bf(acc[m][n][3]) << 16);
        const int c2 = (m&1)*2 + (lg>>1);
        char* dst = (char*)VT + (size_t)bh*262144
                  + (size_t)(((row0 & 2047) >> 5) + (m>>1))*4096
                  + af*64 + ((c2 ^ (af&3))<<4) + (lg&1)*8;
        *(uint2*)dst = pk;
      } else if (c == 1){
        // K fragment-major store
        const unsigned kb = ((unsigned)(af>>5))*512 + ((unsigned)((af>>3)&3))*128 + (unsigned)(af&7);
        #pragma unroll
        for (int r=0;r<4;++r){
          int t = tl0 + m*16 + r;
          K[(size_t)bh*131072 + (t>>5)*2048 + ((t>>4)&1)*1024 + kb + (t&15)*8] = f2bf(acc[m][n][r]);
        }
      } else {
        #pragma unroll
        for (int r=0;r<4;++r){
          int t = tl0 + m*16 + r;
          Q[((size_t)bh*2048 + t)*64 + af] = f2bf(acc[m][n][r] * QSCALE);
        }
      }
    }
  }
}

// ---------- flash attention (P-pipeline + K-in-registers) ----------
// grid 1024 (XCD-swizzled). 4 waves * 32 q-rows. KV tile = 32 keys.
// LDS: V0@0 V1@4096 | P 4 waves x 2 copies x [32][40] u16 @8192. Total 28672 B.
#define NKT 64
#define PLD 40
__global__ __launch_bounds__(256, 4) void k_attn(const u16* __restrict__ Q, const u16* __restrict__ K,
                                                 const u16* __restrict__ VT, u16* __restrict__ OA){
  __shared__ __align__(16) char smem[28672];
  const int lane = threadIdx.x & 63, w = threadIdx.x >> 6;
  const int lg = lane >> 4, li = lane & 15;
  const int swz = (blockIdx.x & 7)*128 + (blockIdx.x >> 3);   // XCD-contiguous
  const int bh = swz >> 4, qt = swz & 15;
  const int q0 = qt*128 + w*32;

  const char* Kfb = (const char*)K + (size_t)bh*262144;
  const char* Vg  = (const char*)VT + (size_t)bh*262144;
  const u16*  Qb  = Q + (size_t)bh*131072;
  u16* pw = (u16*)(smem + 8192) + w*2560;       // + copy*1280 (u16 units)

  const unsigned vsrc = (unsigned)(w*1024 + lane*16);
  const unsigned ldst = (unsigned)(w*1024);
  const unsigned vc   = (unsigned)(((lg) ^ (li&3)) << 4);

  bf16x8 aq[2][2];
  #pragma unroll
  for (int m=0;m<2;++m)
    #pragma unroll
    for (int kd=0;kd<2;++kd)
      aq[m][kd] = *(const bf16x8*)(Qb + (size_t)(q0 + m*16 + li)*64 + kd*32 + lg*8);

  const short one_bf = (short)0x3F80;
  bf16x8 ones = {one_bf,one_bf,one_bf,one_bf,one_bf,one_bf,one_bf,one_bf};

  f32x4 o[2][4] = {};
  f32x4 ls[2] = {};
  bf16x8 ka0_00, ka0_01, ka0_10, ka0_11;   // K bank 0 [n][half]
  bf16x8 ka1_00, ka1_01, ka1_10, ka1_11;   // K bank 1

#define KLOAD(BANK, KT) { const char* kb_ = Kfb + (size_t)(KT)*4096; \
    ka##BANK##_00 = *(const bf16x8*)(kb_ +        lane*16); \
    ka##BANK##_01 = *(const bf16x8*)(kb_ + 1024 + lane*16); \
    ka##BANK##_10 = *(const bf16x8*)(kb_ + 2048 + lane*16); \
    ka##BANK##_11 = *(const bf16x8*)(kb_ + 3072 + lane*16); }

  auto QKEXP = [&](bf16x8 b00, bf16x8 b01, bf16x8 b10, bf16x8 b11, u16* pW){
    #pragma unroll
    for (int n=0;n<2;++n){
      bf16x8 bk0 = n ? b10 : b00;
      bf16x8 bk1 = n ? b11 : b01;
      #pragma unroll
      for (int m=0;m<2;++m){
        f32x4 s = {0.f,0.f,0.f,0.f};   // S^T: row k=n*16+4lg+r, col q=m*16+li
        s = __builtin_amdgcn_mfma_f32_16x16x32_bf16(bk0, aq[m][0], s, 0, 0, 0);
        s = __builtin_amdgcn_mfma_f32_16x16x32_bf16(bk1, aq[m][1], s, 0, 0, 0);
        uint2 pk;
        pk.x = cvtpk(__builtin_exp2f(s[0]), __builtin_exp2f(s[1]));
        pk.y = cvtpk(__builtin_exp2f(s[2]), __builtin_exp2f(s[3]));
        *(uint2*)(pW + (size_t)(m*16 + li)*PLD + n*16 + lg*4) = pk;
      }
    }
  };
  auto PV = [&](const char* sV, const u16* pR){
    bf16x8 pa0 = *(const bf16x8*)(pR + (size_t)(     li)*PLD + lg*8);
    bf16x8 pa1 = *(const bf16x8*)(pR + (size_t)(16 + li)*PLD + lg*8);
    __builtin_amdgcn_s_setprio(1);
    #pragma unroll
    for (int nd=0;nd<4;++nd){
      bf16x8 bv = *(const bf16x8*)(sV + (nd*16 + li)*64 + vc);
      o[0][nd] = __builtin_amdgcn_mfma_f32_16x16x32_bf16(pa0, bv, o[0][nd], 0, 0, 0);
      o[1][nd] = __builtin_amdgcn_mfma_f32_16x16x32_bf16(pa1, bv, o[1][nd], 0, 0, 0);
    }
    ls[0] = __builtin_amdgcn_mfma_f32_16x16x32_bf16(pa0, ones, ls[0], 0, 0, 0);
    ls[1] = __builtin_amdgcn_mfma_f32_16x16x32_bf16(pa1, ones, ls[1], 0, 0, 0);
    __builtin_amdgcn_s_setprio(0);
  };

// one pipeline iteration; PR is a literal 0/1 so K banks are compile-time
#define AITER(KT, PR, PN) { \
    gload16(Vg + (size_t)((KT)+1)*4096u + vsrc, smem + (PN)*4096 + ldst); \
    if ((KT) + 2 < NKT) KLOAD(PR, (KT)+2); \
    QKEXP(ka##PN##_00, ka##PN##_01, ka##PN##_10, ka##PN##_11, pw + (PN)*1280); \
    PV(smem + (PR)*4096, pw + (PR)*1280); \
    asm volatile("s_waitcnt vmcnt(0)" ::: "memory"); \
    __builtin_amdgcn_s_barrier(); }

  // prologue: V(0)->Vbuf0, K(0)->bank0, K(1)->bank1; drain; QKEXP(0)->pbuf0
  gload16(Vg + vsrc, smem + ldst);
  KLOAD(0, 0);
  KLOAD(1, 1);
  asm volatile("s_waitcnt vmcnt(0)" ::: "memory");
  __builtin_amdgcn_s_barrier();
  QKEXP(ka0_00, ka0_01, ka0_10, ka0_11, pw);
  __builtin_amdgcn_s_barrier();

  for (int base = 0; base < NKT-2; base += 2){
    AITER(base,   0, 1);
    AITER(base+1, 1, 0);
  }
  AITER(NKT-2, 0, 1);                              // kt=62 (K guard skips)
  PV(smem + 4096, pw + 1280);                      // PV(63)

  // store O in OA layout (R13-verified)
  const int b_ = bh >> 4, h = bh & 15;
  #pragma unroll
  for (int m=0;m<2;++m){
    const int tile = (b_*2048 + q0 + m*16) >> 4;
    #pragma unroll
    for (int r=0;r<4;++r){
      float linv = 1.0f / ls[m][r];
      #pragma unroll
      for (int nd=0;nd<4;++nd){
        OA[(size_t)(((tile*16 + h)*2 + (nd>>1))*512)
           + (lg*4 + r)*32 + ((nd&1)*2 + (li>>3))*8 + (li&7)] = f2bf(o[m][nd][r] * linv);
      }
    }
  }
#undef AITER
#undef KLOAD
}

// ---------- output projection (XCD-affine; fragment-major weights + OA) ----------
__global__ __launch_bounds__(256) void k_proj(const u16* __restrict__ OA, const u16* __restrict__ wot,
                                              float* __restrict__ out){
  const int lane = threadIdx.x & 63, wv = threadIdx.x >> 6;
  const int lg = lane >> 4, li = lane & 15;
  const int blk = blockIdx.x;
  const int xcd = blk & 7, idx = blk >> 3;
  const int rowTile = (idx >> 3)*8 + xcd;
  const int colTile = idx & 7;
  const int row0 = rowTile*128 + wv*32;
  const int part = colTile >> 2;
  const int ft   = colTile & 3;
  const int f0   = ft*128;

  f32x4 acc[2][8] = {};
  const u16* wbase = wot + (size_t)part*262144 + (size_t)ft*65536;
  const unsigned aoff = (unsigned)(li*32 + lg*8);
  #pragma unroll 4
  for (int ks = 0; ks < 16; ++ks){
    bf16x8 a[2];
    #pragma unroll
    for (int m=0;m<2;++m)
      a[m] = *(const bf16x8*)(OA + (size_t)((((rowTile*8 + wv*2 + m)*16 + ks)*2 + part)*512) + aoff);
    #pragma unroll
    for (int n=0;n<8;++n){
      bf16x8 b = *(const bf16x8*)(wbase + ks*4096 + n*512 + lane*8);
      #pragma unroll
      for (int m=0;m<2;++m)
        acc[m][n] = __builtin_amdgcn_mfma_f32_16x16x32_bf16(a[m], b, acc[m][n], 0, 0, 0);
    }
  }
  float* obp = out + (size_t)part*(8192u*512u);
  #pragma unroll
  for (int m=0;m<2;++m)
    #pragma unroll
    for (int n=0;n<8;++n)
      #pragma unroll
      for (int r=0;r<4;++r)
        obp[(size_t)(row0 + m*16 + lg*4 + r)*512 + f0 + n*16 + li] = acc[m][n][r];
}

extern "C" void kernel_launch(void* const* d_in, const int* in_sizes, int n_in,
                              void* d_out, int out_size, void* d_ws, size_t ws_size,
                              hipStream_t stream){
  const float* x   = (const float*)d_in[0];
  const float* wqc = (const float*)d_in[1];
  const float* wqp = (const float*)d_in[2];
  const float* woc = (const float*)d_in[3];
  const float* wop = (const float*)d_in[4];

  char* ws = (char*)d_ws;
  u16* xA  = (u16*)(ws);
  u16* Q   = (u16*)(ws + 16777216);
  u16* K   = (u16*)(ws + 2*16777216);
  u16* VT  = (u16*)(ws + 3*16777216);
  u16* wqt = (u16*)(ws + 4*16777216);
  u16* wot = (u16*)(ws + 4*16777216 + 3145728);
  u16* OA  = xA;   // xA dead after k_qkv
  float* out = (float*)d_out;

  k_prep <<<16384, 256, 0, stream>>>((const float4*)x, xA, wqc, wqp, wqt, woc, wop, wot);
  k_qkv  <<<1024,  256, 0, stream>>>(xA, wqt, Q, K, VT);
  k_attn <<<1024,  256, 0, stream>>>(Q, K, VT, OA);
  k_proj <<<512,   256, 0, stream>>>(OA, wot, out);
}